// Round 5
// baseline (294.194 us; speedup 1.0000x reference)
//
#include <hip/hip_runtime.h>

#define EMB_D  128   // f32 node row = 1024 B; int8 row = 256 B
#define NBMAX  2048
#define BSHIFT 7     // bucket = head >> 7  (128 nodes = 32 KB of rows per bucket)

// ---------------- pack: f32 row -> int8 (re,im interleaved) + per-row scale ----------
__global__ __launch_bounds__(256) void pack_int8_kernel(
    const float* __restrict__ node_emb,   // [N, 256] f32
    uint2*       __restrict__ tab,        // [N, 32] uint2 (256 B/row)
    float*       __restrict__ scales,     // [N] f32: rowmax/127
    int num_nodes)
{
    const int j   = threadIdx.x & 31;
    const int hw  = (blockIdx.x * blockDim.x + threadIdx.x) >> 5;
    const int nHW = (gridDim.x * blockDim.x) >> 5;

    for (int n = hw; n < num_nodes; n += nHW) {
        const float* rowp = node_emb + (size_t)n * (2 * EMB_D);
        const float4 re = *reinterpret_cast<const float4*>(rowp + 4 * j);
        const float4 im = *reinterpret_cast<const float4*>(rowp + EMB_D + 4 * j);

        float m = fmaxf(fmaxf(fmaxf(fabsf(re.x), fabsf(re.y)), fmaxf(fabsf(re.z), fabsf(re.w))),
                        fmaxf(fmaxf(fabsf(im.x), fabsf(im.y)), fmaxf(fabsf(im.z), fabsf(im.w))));
        #pragma unroll
        for (int off = 1; off <= 16; off <<= 1)
            m = fmaxf(m, __shfl_xor(m, off, 64));   // stays within the 32-lane half

        const float inv = (m > 0.f) ? 127.0f / m : 0.f;

        #define Q(x) ((unsigned)((int)rintf((x) * inv)) & 255u)
        const unsigned lo = Q(re.x) | (Q(im.x) << 8) | (Q(re.y) << 16) | (Q(im.y) << 24);
        const unsigned hi = Q(re.z) | (Q(im.z) << 8) | (Q(re.w) << 16) | (Q(im.w) << 24);
        #undef Q

        tab[(size_t)n * 32 + j] = make_uint2(lo, hi);
        if (j == 0) scales[n] = m * (1.0f / 127.0f);
    }
}

// ---------------- sort-by-head-bucket machinery ----------------
__global__ __launch_bounds__(256) void init_kernel(
    int* __restrict__ hist, int nb,
    int4* __restrict__ rec, int E, int paddedE)
{
    const int i = blockIdx.x * blockDim.x + threadIdx.x;
    if (i < nb) hist[i] = 0;
    if (i < paddedE - E) rec[E + i] = make_int4(0, 0, 0x7fffffff, 0); // pad: oe=INT_MAX
}

__global__ __launch_bounds__(256) void hist_kernel(
    const int* __restrict__ heads, int E, int* __restrict__ hist, int nb)
{
    __shared__ int lh[NBMAX];
    for (int i = threadIdx.x; i < nb; i += 256) lh[i] = 0;
    __syncthreads();
    for (int e = blockIdx.x * blockDim.x + threadIdx.x; e < E; e += gridDim.x * blockDim.x)
        atomicAdd(&lh[heads[e] >> BSHIFT], 1);
    __syncthreads();
    for (int i = threadIdx.x; i < nb; i += 256) {
        const int v = lh[i];
        if (v) atomicAdd(&hist[i], v);
    }
}

// exclusive prefix over <=2048 bins, single block of 256 threads
__global__ __launch_bounds__(256) void scan_kernel(
    const int* __restrict__ hist, int* __restrict__ cursor, int nb)
{
    __shared__ int sums[256];
    int local[8];
    const int base = threadIdx.x * 8;
    int s = 0;
    #pragma unroll
    for (int k = 0; k < 8; ++k) {
        const int i = base + k;
        const int v = (i < nb) ? hist[i] : 0;
        local[k] = s; s += v;
    }
    sums[threadIdx.x] = s;
    __syncthreads();
    if (threadIdx.x == 0) {
        int a = 0;
        for (int i = 0; i < 256; ++i) { const int t = sums[i]; sums[i] = a; a += t; }
    }
    __syncthreads();
    const int off = sums[threadIdx.x];
    #pragma unroll
    for (int k = 0; k < 8; ++k) {
        const int i = base + k;
        if (i < nb) cursor[i] = off + local[k];
    }
}

// rec[pos] = {h, t, orig_e, bitcast(scale_h*scale_t)}
__global__ __launch_bounds__(256) void scatter_kernel(
    const int* __restrict__ idx, int E,
    const float* __restrict__ scales,
    int* __restrict__ cursor, int4* __restrict__ rec)
{
    for (int e = blockIdx.x * blockDim.x + threadIdx.x; e < E; e += gridDim.x * blockDim.x) {
        const int h = idx[e];
        const int t = idx[E + e];
        const float s = scales[h] * scales[t];
        const int pos = atomicAdd(&cursor[h >> BSHIFT], 1);
        rec[pos] = make_int4(h, t, e, __float_as_int(s));
    }
}

// ---------------- gather over head-sorted records ----------------
__device__ __forceinline__ float score4_i8(const uint2 hq, const uint2 tq,
                                           const float4 rr, const float4 ri) {
    union U { uint2 u; signed char c[8]; };
    U H, T; H.u = hq; T.u = tq;
    float acc = 0.f;
#define DIM_TERM(d, C) { \
        const float hr = (float)H.c[2*(d)], hi = (float)H.c[2*(d)+1]; \
        const float tr = (float)T.c[2*(d)], ti = (float)T.c[2*(d)+1]; \
        acc += rr.C * (hr * tr + hi * ti) + ri.C * (hr * ti - hi * tr); }
    DIM_TERM(0, x) DIM_TERM(1, y) DIM_TERM(2, z) DIM_TERM(3, w)
#undef DIM_TERM
    return acc;
}

// CHUNKED tile assignment: each block owns a contiguous range of sorted tiles so
// its head rows stay within ~1 bucket (32 KB, L1-resident). 4 waves stride the chunk.
__global__ __launch_bounds__(256) void gather_sorted_kernel(
    const uint2* __restrict__ tab,        // [N, 32] int8 rows
    const int4*  __restrict__ rec,        // [paddedE] sorted {h,t,oe,s}
    const float* __restrict__ rel_emb,    // [256] f32
    float*       __restrict__ out,        // [E]
    int num_edges, int nTiles)
{
    const int lane = threadIdx.x & 63;
    const int j    = lane & 31;
    const int sub  = lane >> 5;

    const float4 rr = reinterpret_cast<const float4*>(rel_emb)[j];
    const float4 ri = reinterpret_cast<const float4*>(rel_emb + EMB_D)[j];

    const int tilesPerBlock = (nTiles + (int)gridDim.x - 1) / (int)gridDim.x;
    const int tBeg = blockIdx.x * tilesPerBlock;
    const int tEnd = min(tBeg + tilesPerBlock, nTiles);
    const int wid  = threadIdx.x >> 6;

    for (int tile = tBeg + wid; tile < tEnd; tile += 4) {
        const int base = tile << 3;   // 8 edges per tile; this sub handles 2k+sub
        const int4 r0 = rec[base + 0 + sub];
        const int4 r1 = rec[base + 2 + sub];
        const int4 r2 = rec[base + 4 + sub];
        const int4 r3 = rec[base + 6 + sub];

        const uint2 hv0 = tab[(size_t)r0.x * 32 + j];
        const uint2 tv0 = tab[(size_t)r0.y * 32 + j];
        const uint2 hv1 = tab[(size_t)r1.x * 32 + j];
        const uint2 tv1 = tab[(size_t)r1.y * 32 + j];
        const uint2 hv2 = tab[(size_t)r2.x * 32 + j];
        const uint2 tv2 = tab[(size_t)r2.y * 32 + j];
        const uint2 hv3 = tab[(size_t)r3.x * 32 + j];
        const uint2 tv3 = tab[(size_t)r3.y * 32 + j];

        float acc0 = score4_i8(hv0, tv0, rr, ri);
        float acc1 = score4_i8(hv1, tv1, rr, ri);
        float acc2 = score4_i8(hv2, tv2, rr, ri);
        float acc3 = score4_i8(hv3, tv3, rr, ri);

        #pragma unroll
        for (int off = 1; off <= 16; off <<= 1) {
            acc0 += __shfl_xor(acc0, off, 64);
            acc1 += __shfl_xor(acc1, off, 64);
            acc2 += __shfl_xor(acc2, off, 64);
            acc3 += __shfl_xor(acc3, off, 64);
        }

        if (j == 0) {
            if (r0.z < num_edges) out[r0.z] = acc0 * __int_as_float(r0.w);
            if (r1.z < num_edges) out[r1.z] = acc1 * __int_as_float(r1.w);
            if (r2.z < num_edges) out[r2.z] = acc2 * __int_as_float(r2.w);
            if (r3.z < num_edges) out[r3.z] = acc3 * __int_as_float(r3.w);
        }
    }
}

// ---------------- fallback: direct f32 gather (ws too small / odd shapes) ----------
__global__ __launch_bounds__(256) void complex_score_f32_kernel(
    const float* __restrict__ node_emb, const float* __restrict__ rel_emb,
    const int* __restrict__ idx, float* __restrict__ out, int num_edges)
{
    const int lane = threadIdx.x & 63;
    const int j = lane & 31, sub = lane >> 5;
    const float4 rr = reinterpret_cast<const float4*>(rel_emb)[j];
    const float4 ri = reinterpret_cast<const float4*>(rel_emb + EMB_D)[j];
    const int w = blockIdx.x * (blockDim.x >> 6) + (threadIdx.x >> 6);
    const int nWaves = gridDim.x * (blockDim.x >> 6);
    for (int e = 2 * w + sub; e < num_edges; e += 2 * nWaves) {
        const int h = idx[e], t = idx[num_edges + e];
        const float4* hp = reinterpret_cast<const float4*>(node_emb + (size_t)h * (2 * EMB_D));
        const float4* tp = reinterpret_cast<const float4*>(node_emb + (size_t)t * (2 * EMB_D));
        const float4 hr = hp[j], hi = hp[32 + j], tr = tp[j], ti = tp[32 + j];
        float acc;
        acc  = rr.x * (hr.x * tr.x + hi.x * ti.x) + ri.x * (hr.x * ti.x - hi.x * tr.x);
        acc += rr.y * (hr.y * tr.y + hi.y * ti.y) + ri.y * (hr.y * ti.y - hi.y * tr.y);
        acc += rr.z * (hr.z * tr.z + hi.z * ti.z) + ri.z * (hr.z * ti.z - hi.z * tr.z);
        acc += rr.w * (hr.w * tr.w + hi.w * ti.w) + ri.w * (hr.w * ti.w - hi.w * tr.w);
        #pragma unroll
        for (int off = 1; off <= 16; off <<= 1) acc += __shfl_xor(acc, off, 64);
        if (j == 0) out[e] = acc;
    }
}

extern "C" void kernel_launch(void* const* d_in, const int* in_sizes, int n_in,
                              void* d_out, int out_size, void* d_ws, size_t ws_size,
                              hipStream_t stream) {
    const float* node_emb = (const float*)d_in[0];   // [N, 256] f32
    const float* rel_emb  = (const float*)d_in[1];   // [1, 256] f32
    const int*   idx      = (const int*)d_in[2];     // [2, E] int
    float*       out      = (float*)d_out;           // [E] f32

    const int num_nodes = in_sizes[0] / (2 * EMB_D);
    const int num_edges = in_sizes[2] / 2;

    const int nb      = ((num_nodes - 1) >> BSHIFT) + 1;          // buckets
    const int paddedE = (num_edges + 7) & ~7;
    const int nTiles  = paddedE >> 3;

    // ws layout: tab | scales | rec (16B-aligned) | hist | cursor
    const size_t tab_b   = (size_t)num_nodes * 256;
    const size_t sc_b    = (size_t)num_nodes * sizeof(float);
    const size_t rec_off = (tab_b + sc_b + 15) & ~(size_t)15;
    const size_t rec_b   = (size_t)paddedE * sizeof(int4);
    const size_t hist_off = rec_off + rec_b;
    const size_t need     = hist_off + 2 * (size_t)NBMAX * sizeof(int);

    if (ws_size >= need && nb <= NBMAX && num_edges >= 8) {
        uint2* tab    = (uint2*)d_ws;
        float* scales = (float*)((char*)d_ws + tab_b);
        int4*  rec    = (int4*)((char*)d_ws + rec_off);
        int*   hist   = (int*)((char*)d_ws + hist_off);
        int*   cursor = hist + NBMAX;

        init_kernel<<<8, 256, 0, stream>>>(hist, nb, rec, num_edges, paddedE);
        pack_int8_kernel<<<2048, 256, 0, stream>>>(node_emb, tab, scales, num_nodes);
        hist_kernel<<<256, 256, 0, stream>>>(idx, num_edges, hist, nb);
        scan_kernel<<<1, 256, 0, stream>>>(hist, cursor, nb);
        scatter_kernel<<<512, 256, 0, stream>>>(idx, num_edges, scales, cursor, rec);
        gather_sorted_kernel<<<2048, 256, 0, stream>>>(tab, rec, rel_emb, out,
                                                       num_edges, nTiles);
    } else {
        complex_score_f32_kernel<<<2048, 256, 0, stream>>>(node_emb, rel_emb, idx, out, num_edges);
    }
}

// Round 6
// 196.266 us; speedup vs baseline: 1.4990x; 1.4990x over previous
//
#include <hip/hip_runtime.h>

#define EMB_D  128   // f32 node row = 1024 B; int8 row = 256 B
#define NBMAX  2048
#define BSHIFT 7     // bucket = head >> 7 (128 nodes = 32 KB of int8 rows per bucket)
#define SBLK   128   // blocks in hist/scatter passes

// ---------------- pack: f32 row -> int8 (re,im interleaved) + per-row scale ----------
__global__ __launch_bounds__(256) void pack_int8_kernel(
    const float* __restrict__ node_emb,   // [N, 256] f32
    uint2*       __restrict__ tab,        // [N, 32] uint2 (256 B/row)
    float*       __restrict__ scales,     // [N] f32: rowmax/127
    int num_nodes)
{
    const int j   = threadIdx.x & 31;
    const int hw  = (blockIdx.x * blockDim.x + threadIdx.x) >> 5;
    const int nHW = (gridDim.x * blockDim.x) >> 5;

    for (int n = hw; n < num_nodes; n += nHW) {
        const float* rowp = node_emb + (size_t)n * (2 * EMB_D);
        const float4 re = *reinterpret_cast<const float4*>(rowp + 4 * j);
        const float4 im = *reinterpret_cast<const float4*>(rowp + EMB_D + 4 * j);

        float m = fmaxf(fmaxf(fmaxf(fabsf(re.x), fabsf(re.y)), fmaxf(fabsf(re.z), fabsf(re.w))),
                        fmaxf(fmaxf(fabsf(im.x), fabsf(im.y)), fmaxf(fabsf(im.z), fabsf(im.w))));
        #pragma unroll
        for (int off = 1; off <= 16; off <<= 1)
            m = fmaxf(m, __shfl_xor(m, off, 64));   // within the 32-lane half

        const float inv = (m > 0.f) ? 127.0f / m : 0.f;

        #define Q(x) ((unsigned)((int)rintf((x) * inv)) & 255u)
        const unsigned lo = Q(re.x) | (Q(im.x) << 8) | (Q(re.y) << 16) | (Q(im.y) << 24);
        const unsigned hi = Q(re.z) | (Q(im.z) << 8) | (Q(re.w) << 16) | (Q(im.w) << 24);
        #undef Q

        tab[(size_t)n * 32 + j] = make_uint2(lo, hi);
        if (j == 0) scales[n] = m * (1.0f / 127.0f);
    }
}

// ---------------- deterministic counting sort (NO global atomics) ----------------
__global__ __launch_bounds__(256) void init_pad_kernel(
    int4* __restrict__ rec, int E, int paddedE)
{
    const int i = blockIdx.x * blockDim.x + threadIdx.x;
    if (i < paddedE - E) rec[E + i] = make_int4(0, 0, 0x7fffffff, 0); // oe=INT_MAX
}

// A: per-block LDS histogram -> partHist[block][bin] (plain writes)
__global__ __launch_bounds__(256) void hist_part_kernel(
    const int* __restrict__ heads, int E, int chunk,
    int* __restrict__ partHist, int nb)
{
    __shared__ int lh[NBMAX];
    for (int i = threadIdx.x; i < nb; i += 256) lh[i] = 0;
    __syncthreads();
    const int beg = blockIdx.x * chunk;
    const int end = min(beg + chunk, E);
    for (int e = beg + threadIdx.x; e < end; e += 256)
        atomicAdd(&lh[heads[e] >> BSHIFT], 1);          // LDS atomics only
    __syncthreads();
    int* row = partHist + (size_t)blockIdx.x * NBMAX;
    for (int i = threadIdx.x; i < nb; i += 256) row[i] = lh[i];
}

// B1: binTotal[b] = sum over blocks
__global__ __launch_bounds__(256) void bintotal_kernel(
    const int* __restrict__ partHist, int* __restrict__ binTotal, int nb)
{
    const int b = blockIdx.x * 256 + threadIdx.x;
    if (b >= nb) return;
    int s = 0;
    #pragma unroll 4
    for (int k = 0; k < SBLK; ++k) s += partHist[(size_t)k * NBMAX + b];
    binTotal[b] = s;
}

// B2: exclusive prefix over <=2048 bins, single block
__global__ __launch_bounds__(256) void scan_kernel(
    const int* __restrict__ hist, int* __restrict__ base, int nb)
{
    __shared__ int sums[256];
    int local[8];
    const int b0 = threadIdx.x * 8;
    int s = 0;
    #pragma unroll
    for (int k = 0; k < 8; ++k) {
        const int i = b0 + k;
        const int v = (i < nb) ? hist[i] : 0;
        local[k] = s; s += v;
    }
    sums[threadIdx.x] = s;
    __syncthreads();
    if (threadIdx.x == 0) {
        int a = 0;
        for (int i = 0; i < 256; ++i) { const int t = sums[i]; sums[i] = a; a += t; }
    }
    __syncthreads();
    const int off = sums[threadIdx.x];
    #pragma unroll
    for (int k = 0; k < 8; ++k) {
        const int i = b0 + k;
        if (i < nb) base[i] = off + local[k];
    }
}

// B3: partHist[blk][b] <- binBase[b] + prefix over blocks (in place: becomes partBase)
__global__ __launch_bounds__(256) void blockbase_kernel(
    int* __restrict__ partHist, const int* __restrict__ binBase, int nb)
{
    const int b = blockIdx.x * 256 + threadIdx.x;
    if (b >= nb) return;
    int run = binBase[b];
    for (int k = 0; k < SBLK; ++k) {
        const size_t o = (size_t)k * NBMAX + b;
        const int v = partHist[o];
        partHist[o] = run;
        run += v;
    }
}

// C: scatter with LDS cursors seeded from partBase — zero global atomics.
// rec[pos] = {h, t, orig_e, bitcast(scale_h*scale_t)}
__global__ __launch_bounds__(256) void scatter_det_kernel(
    const int* __restrict__ idx, int E, int chunk,
    const float* __restrict__ scales,
    const int* __restrict__ partBase, int4* __restrict__ rec, int nb)
{
    __shared__ int cur[NBMAX];
    const int* row = partBase + (size_t)blockIdx.x * NBMAX;
    for (int i = threadIdx.x; i < nb; i += 256) cur[i] = row[i];
    __syncthreads();
    const int beg = blockIdx.x * chunk;
    const int end = min(beg + chunk, E);
    for (int e = beg + threadIdx.x; e < end; e += 256) {
        const int h = idx[e];
        const int t = idx[E + e];
        const float s = scales[h] * scales[t];
        const int pos = atomicAdd(&cur[h >> BSHIFT], 1);   // LDS atomic
        rec[pos] = make_int4(h, t, e, __float_as_int(s));
    }
}

// ---------------- gather over head-sorted records ----------------
__device__ __forceinline__ float score4_i8(const uint2 hq, const uint2 tq,
                                           const float4 rr, const float4 ri) {
    union U { uint2 u; signed char c[8]; };
    U H, T; H.u = hq; T.u = tq;
    float acc = 0.f;
#define DIM_TERM(d, C) { \
        const float hr = (float)H.c[2*(d)], hi = (float)H.c[2*(d)+1]; \
        const float tr = (float)T.c[2*(d)], ti = (float)T.c[2*(d)+1]; \
        acc += rr.C * (hr * tr + hi * ti) + ri.C * (hr * ti - hi * tr); }
    DIM_TERM(0, x) DIM_TERM(1, y) DIM_TERM(2, z) DIM_TERM(3, w)
#undef DIM_TERM
    return acc;
}

// CHUNKED tiles: each block owns a contiguous sorted range -> head rows ~1 bucket
// (32 KB, L1/L2-local). 4 waves stride the chunk. 8 edges per wave-iteration.
__global__ __launch_bounds__(256) void gather_sorted_kernel(
    const uint2* __restrict__ tab,        // [N, 32] int8 rows
    const int4*  __restrict__ rec,        // [paddedE] sorted {h,t,oe,s}
    const float* __restrict__ rel_emb,    // [256] f32
    float*       __restrict__ out,        // [E]
    int num_edges, int nTiles)
{
    const int lane = threadIdx.x & 63;
    const int j    = lane & 31;
    const int sub  = lane >> 5;

    const float4 rr = reinterpret_cast<const float4*>(rel_emb)[j];
    const float4 ri = reinterpret_cast<const float4*>(rel_emb + EMB_D)[j];

    const int tilesPerBlock = (nTiles + (int)gridDim.x - 1) / (int)gridDim.x;
    const int tBeg = blockIdx.x * tilesPerBlock;
    const int tEnd = min(tBeg + tilesPerBlock, nTiles);
    const int wid  = threadIdx.x >> 6;

    for (int tile = tBeg + wid; tile < tEnd; tile += 4) {
        const int base = tile << 3;
        const int4 r0 = rec[base + 0 + sub];
        const int4 r1 = rec[base + 2 + sub];
        const int4 r2 = rec[base + 4 + sub];
        const int4 r3 = rec[base + 6 + sub];

        const uint2 hv0 = tab[(size_t)r0.x * 32 + j];
        const uint2 tv0 = tab[(size_t)r0.y * 32 + j];
        const uint2 hv1 = tab[(size_t)r1.x * 32 + j];
        const uint2 tv1 = tab[(size_t)r1.y * 32 + j];
        const uint2 hv2 = tab[(size_t)r2.x * 32 + j];
        const uint2 tv2 = tab[(size_t)r2.y * 32 + j];
        const uint2 hv3 = tab[(size_t)r3.x * 32 + j];
        const uint2 tv3 = tab[(size_t)r3.y * 32 + j];

        float acc0 = score4_i8(hv0, tv0, rr, ri);
        float acc1 = score4_i8(hv1, tv1, rr, ri);
        float acc2 = score4_i8(hv2, tv2, rr, ri);
        float acc3 = score4_i8(hv3, tv3, rr, ri);

        #pragma unroll
        for (int off = 1; off <= 16; off <<= 1) {
            acc0 += __shfl_xor(acc0, off, 64);
            acc1 += __shfl_xor(acc1, off, 64);
            acc2 += __shfl_xor(acc2, off, 64);
            acc3 += __shfl_xor(acc3, off, 64);
        }

        if (j == 0) {
            if (r0.z < num_edges) out[r0.z] = acc0 * __int_as_float(r0.w);
            if (r1.z < num_edges) out[r1.z] = acc1 * __int_as_float(r1.w);
            if (r2.z < num_edges) out[r2.z] = acc2 * __int_as_float(r2.w);
            if (r3.z < num_edges) out[r3.z] = acc3 * __int_as_float(r3.w);
        }
    }
}

// ---------------- fallback 1: unsorted i8 gather (R4) ----------------
__global__ __launch_bounds__(256) void complex_score_i8_kernel(
    const uint2* __restrict__ tab, const float* __restrict__ scales,
    const float* __restrict__ rel_emb, const int* __restrict__ idx,
    float* __restrict__ out, int num_edges)
{
    const int lane = threadIdx.x & 63;
    const int j = lane & 31, sub = lane >> 5;
    const float4 rr = reinterpret_cast<const float4*>(rel_emb)[j];
    const float4 ri = reinterpret_cast<const float4*>(rel_emb + EMB_D)[j];
    const int w = blockIdx.x * (blockDim.x >> 6) + (threadIdx.x >> 6);
    const int nWaves = gridDim.x * (blockDim.x >> 6);
    for (int e = 2 * w + sub; e < num_edges; e += 2 * nWaves) {
        const int h = idx[e], t = idx[num_edges + e];
        float acc = score4_i8(tab[(size_t)h * 32 + j], tab[(size_t)t * 32 + j], rr, ri);
        #pragma unroll
        for (int off = 1; off <= 16; off <<= 1) acc += __shfl_xor(acc, off, 64);
        if (j == 0) out[e] = acc * scales[h] * scales[t];
    }
}

// ---------------- fallback 2: direct f32 gather ----------------
__global__ __launch_bounds__(256) void complex_score_f32_kernel(
    const float* __restrict__ node_emb, const float* __restrict__ rel_emb,
    const int* __restrict__ idx, float* __restrict__ out, int num_edges)
{
    const int lane = threadIdx.x & 63;
    const int j = lane & 31, sub = lane >> 5;
    const float4 rr = reinterpret_cast<const float4*>(rel_emb)[j];
    const float4 ri = reinterpret_cast<const float4*>(rel_emb + EMB_D)[j];
    const int w = blockIdx.x * (blockDim.x >> 6) + (threadIdx.x >> 6);
    const int nWaves = gridDim.x * (blockDim.x >> 6);
    for (int e = 2 * w + sub; e < num_edges; e += 2 * nWaves) {
        const int h = idx[e], t = idx[num_edges + e];
        const float4* hp = reinterpret_cast<const float4*>(node_emb + (size_t)h * (2 * EMB_D));
        const float4* tp = reinterpret_cast<const float4*>(node_emb + (size_t)t * (2 * EMB_D));
        const float4 hr = hp[j], hi = hp[32 + j], tr = tp[j], ti = tp[32 + j];
        float acc;
        acc  = rr.x * (hr.x * tr.x + hi.x * ti.x) + ri.x * (hr.x * ti.x - hi.x * tr.x);
        acc += rr.y * (hr.y * tr.y + hi.y * ti.y) + ri.y * (hr.y * ti.y - hi.y * tr.y);
        acc += rr.z * (hr.z * tr.z + hi.z * ti.z) + ri.z * (hr.z * ti.z - hi.z * tr.z);
        acc += rr.w * (hr.w * tr.w + hi.w * ti.w) + ri.w * (hr.w * ti.w - hi.w * tr.w);
        #pragma unroll
        for (int off = 1; off <= 16; off <<= 1) acc += __shfl_xor(acc, off, 64);
        if (j == 0) out[e] = acc;
    }
}

extern "C" void kernel_launch(void* const* d_in, const int* in_sizes, int n_in,
                              void* d_out, int out_size, void* d_ws, size_t ws_size,
                              hipStream_t stream) {
    const float* node_emb = (const float*)d_in[0];   // [N, 256] f32
    const float* rel_emb  = (const float*)d_in[1];   // [1, 256] f32
    const int*   idx      = (const int*)d_in[2];     // [2, E] int
    float*       out      = (float*)d_out;           // [E] f32

    const int num_nodes = in_sizes[0] / (2 * EMB_D);
    const int num_edges = in_sizes[2] / 2;

    const int nb      = ((num_nodes - 1) >> BSHIFT) + 1;
    const int paddedE = (num_edges + 7) & ~7;
    const int nTiles  = paddedE >> 3;
    const int chunk   = (num_edges + SBLK - 1) / SBLK;

    // ws layout: tab | scales | rec | partHist[SBLK][NBMAX] | binTotal | binBase
    const size_t tab_b    = (size_t)num_nodes * 256;
    const size_t sc_b     = (size_t)num_nodes * sizeof(float);
    const size_t rec_off  = (tab_b + sc_b + 15) & ~(size_t)15;
    const size_t rec_b    = (size_t)paddedE * sizeof(int4);
    const size_t ph_off   = rec_off + rec_b;
    const size_t ph_b     = (size_t)SBLK * NBMAX * sizeof(int);
    const size_t bt_off   = ph_off + ph_b;
    const size_t need_all = bt_off + 2 * (size_t)NBMAX * sizeof(int);
    const size_t need_i8  = tab_b + sc_b;

    if (ws_size >= need_all && nb <= NBMAX && num_edges >= 8) {
        uint2* tab      = (uint2*)d_ws;
        float* scales   = (float*)((char*)d_ws + tab_b);
        int4*  rec      = (int4*)((char*)d_ws + rec_off);
        int*   partHist = (int*)((char*)d_ws + ph_off);
        int*   binTotal = (int*)((char*)d_ws + bt_off);
        int*   binBase  = binTotal + NBMAX;
        const int binGrid = (nb + 255) / 256;

        init_pad_kernel<<<8, 256, 0, stream>>>(rec, num_edges, paddedE);
        pack_int8_kernel<<<2048, 256, 0, stream>>>(node_emb, tab, scales, num_nodes);
        hist_part_kernel<<<SBLK, 256, 0, stream>>>(idx, num_edges, chunk, partHist, nb);
        bintotal_kernel<<<binGrid, 256, 0, stream>>>(partHist, binTotal, nb);
        scan_kernel<<<1, 256, 0, stream>>>(binTotal, binBase, nb);
        blockbase_kernel<<<binGrid, 256, 0, stream>>>(partHist, binBase, nb);
        scatter_det_kernel<<<SBLK, 256, 0, stream>>>(idx, num_edges, chunk, scales,
                                                     partHist, rec, nb);
        gather_sorted_kernel<<<2048, 256, 0, stream>>>(tab, rec, rel_emb, out,
                                                       num_edges, nTiles);
    } else if (ws_size >= need_i8) {
        uint2* tab    = (uint2*)d_ws;
        float* scales = (float*)((char*)d_ws + tab_b);
        pack_int8_kernel<<<2048, 256, 0, stream>>>(node_emb, tab, scales, num_nodes);
        complex_score_i8_kernel<<<2048, 256, 0, stream>>>(tab, scales, rel_emb, idx, out, num_edges);
    } else {
        complex_score_f32_kernel<<<2048, 256, 0, stream>>>(node_emb, rel_emb, idx, out, num_edges);
    }
}

// Round 8
// 134.141 us; speedup vs baseline: 2.1932x; 1.4631x over previous
//
#include <hip/hip_runtime.h>

#define EMB_D 128   // f32 node row = 256 floats = 1024 B; int8 row = 256 B + 4 B scale

typedef int v4i __attribute__((ext_vector_type(4)));   // plain vector: OK for nontemporal builtins

// ---------------- pack: f32 row -> int8 (re,im interleaved) + per-row scale ----------
// Half-wave (32 lanes) per node. Lane j owns dims 4j..4j+3.
__global__ __launch_bounds__(256) void pack_int8_kernel(
    const float* __restrict__ node_emb,   // [N, 256] f32
    uint2*       __restrict__ tab,        // [N, 32] uint2 (256 B/row)
    float*       __restrict__ scales,     // [N] f32: rowmax/127
    int num_nodes)
{
    const int j   = threadIdx.x & 31;
    const int hw  = (blockIdx.x * blockDim.x + threadIdx.x) >> 5;
    const int nHW = (gridDim.x * blockDim.x) >> 5;

    for (int n = hw; n < num_nodes; n += nHW) {
        const float* rowp = node_emb + (size_t)n * (2 * EMB_D);
        const float4 re = *reinterpret_cast<const float4*>(rowp + 4 * j);
        const float4 im = *reinterpret_cast<const float4*>(rowp + EMB_D + 4 * j);

        float m = fmaxf(fmaxf(fmaxf(fabsf(re.x), fabsf(re.y)), fmaxf(fabsf(re.z), fabsf(re.w))),
                        fmaxf(fmaxf(fabsf(im.x), fabsf(im.y)), fmaxf(fabsf(im.z), fabsf(im.w))));
        #pragma unroll
        for (int off = 1; off <= 16; off <<= 1)
            m = fmaxf(m, __shfl_xor(m, off, 64));   // stays within the 32-lane half

        const float inv = (m > 0.f) ? 127.0f / m : 0.f;

        #define Q(x) ((unsigned)((int)rintf((x) * inv)) & 255u)
        const unsigned lo = Q(re.x) | (Q(im.x) << 8) | (Q(re.y) << 16) | (Q(im.y) << 24);
        const unsigned hi = Q(re.z) | (Q(im.z) << 8) | (Q(re.w) << 16) | (Q(im.w) << 24);
        #undef Q

        tab[(size_t)n * 32 + j] = make_uint2(lo, hi);
        if (j == 0) scales[n] = m * (1.0f / 127.0f);
    }
}

// un-scaled per-lane partial score over this lane's 4 dims
__device__ __forceinline__ float score4_i8(const uint2 hq, const uint2 tq,
                                           const float4 rr, const float4 ri) {
    union U { uint2 u; signed char c[8]; };
    U H, T; H.u = hq; T.u = tq;
    float acc = 0.f;
#define DIM_TERM(d, C) { \
        const float hr = (float)H.c[2*(d)], hi = (float)H.c[2*(d)+1]; \
        const float tr = (float)T.c[2*(d)], ti = (float)T.c[2*(d)+1]; \
        acc += rr.C * (hr * tr + hi * ti) + ri.C * (hr * ti - hi * tr); }
    DIM_TERM(0, x) DIM_TERM(1, y) DIM_TERM(2, z) DIM_TERM(3, w)
#undef DIM_TERM
    return acc;
}

// Half-wave per edge; one dwordx2 per lane covers a full 256 B row.
// Tile = 8 edges per wave-iteration; 4 interleaved shuffle reductions.
// idx reads and out writes are non-temporal (streaming) so they don't evict
// table rows from L2 — the gather's L2 hit rate is what sets the fetch ratio.
__global__ __launch_bounds__(256) void complex_score_i8_kernel(
    const uint2* __restrict__ tab,        // [N, 32] int8 rows
    const float* __restrict__ scales,     // [N]
    const float* __restrict__ rel_emb,    // [256] f32
    const int*   __restrict__ idx,        // [2, E]
    float*       __restrict__ out,        // [E]
    int num_edges)
{
    const int lane = threadIdx.x & 63;
    const int j    = lane & 31;
    const int sub  = lane >> 5;

    const float4 rr = reinterpret_cast<const float4*>(rel_emb)[j];
    const float4 ri = reinterpret_cast<const float4*>(rel_emb + EMB_D)[j];

    const int w      = blockIdx.x * (blockDim.x >> 6) + (threadIdx.x >> 6);
    const int nWaves = gridDim.x * (blockDim.x >> 6);
    const int nTiles = num_edges >> 3;

    for (int tile = w; tile < nTiles; tile += nWaves) {
        const int base = tile << 3;
        const v4i h03 = __builtin_nontemporal_load(reinterpret_cast<const v4i*>(idx + base));
        const v4i h47 = __builtin_nontemporal_load(reinterpret_cast<const v4i*>(idx + base + 4));
        const v4i t03 = __builtin_nontemporal_load(reinterpret_cast<const v4i*>(idx + num_edges + base));
        const v4i t47 = __builtin_nontemporal_load(reinterpret_cast<const v4i*>(idx + num_edges + base + 4));

        const int h0  = sub ? h03.y : h03.x;
        const int h1  = sub ? h03.w : h03.z;
        const int h2_ = sub ? h47.y : h47.x;
        const int h3_ = sub ? h47.w : h47.z;
        const int t0  = sub ? t03.y : t03.x;
        const int t1  = sub ? t03.w : t03.z;
        const int t2_ = sub ? t47.y : t47.x;
        const int t3_ = sub ? t47.w : t47.z;

        // 8 row loads (256 B each) + 8 scale loads (L2-resident, broadcast)
        const uint2 hv0 = tab[(size_t)h0  * 32 + j];
        const uint2 tv0 = tab[(size_t)t0  * 32 + j];
        const uint2 hv1 = tab[(size_t)h1  * 32 + j];
        const uint2 tv1 = tab[(size_t)t1  * 32 + j];
        const uint2 hv2 = tab[(size_t)h2_ * 32 + j];
        const uint2 tv2 = tab[(size_t)t2_ * 32 + j];
        const uint2 hv3 = tab[(size_t)h3_ * 32 + j];
        const uint2 tv3 = tab[(size_t)t3_ * 32 + j];
        const float s0 = scales[h0]  * scales[t0];
        const float s1 = scales[h1]  * scales[t1];
        const float s2 = scales[h2_] * scales[t2_];
        const float s3 = scales[h3_] * scales[t3_];

        float acc0 = score4_i8(hv0, tv0, rr, ri);
        float acc1 = score4_i8(hv1, tv1, rr, ri);
        float acc2 = score4_i8(hv2, tv2, rr, ri);
        float acc3 = score4_i8(hv3, tv3, rr, ri);

        #pragma unroll
        for (int off = 1; off <= 16; off <<= 1) {
            acc0 += __shfl_xor(acc0, off, 64);
            acc1 += __shfl_xor(acc1, off, 64);
            acc2 += __shfl_xor(acc2, off, 64);
            acc3 += __shfl_xor(acc3, off, 64);
        }

        if (j == 0) {
            __builtin_nontemporal_store(acc0 * s0, &out[base + 0 + sub]);
            __builtin_nontemporal_store(acc1 * s1, &out[base + 2 + sub]);
            __builtin_nontemporal_store(acc2 * s2, &out[base + 4 + sub]);
            __builtin_nontemporal_store(acc3 * s3, &out[base + 6 + sub]);
        }
    }

    // tail (num_edges % 8)
    const int tailStart = nTiles << 3;
    if (w == 0 && tailStart < num_edges) {
        for (int e = tailStart + sub; e < num_edges; e += 2) {
            const int h = idx[e], t = idx[num_edges + e];
            float acc = score4_i8(tab[(size_t)h * 32 + j], tab[(size_t)t * 32 + j], rr, ri);
            #pragma unroll
            for (int off = 1; off <= 16; off <<= 1) acc += __shfl_xor(acc, off, 64);
            if (j == 0) out[e] = acc * scales[h] * scales[t];
        }
    }
}

// ---------------- fallback: direct f32 gather (ws too small / odd shapes) ----------
__global__ __launch_bounds__(256) void complex_score_f32_kernel(
    const float* __restrict__ node_emb, const float* __restrict__ rel_emb,
    const int* __restrict__ idx, float* __restrict__ out, int num_edges)
{
    const int lane = threadIdx.x & 63;
    const int j = lane & 31, sub = lane >> 5;
    const float4 rr = reinterpret_cast<const float4*>(rel_emb)[j];
    const float4 ri = reinterpret_cast<const float4*>(rel_emb + EMB_D)[j];
    const int w = blockIdx.x * (blockDim.x >> 6) + (threadIdx.x >> 6);
    const int nWaves = gridDim.x * (blockDim.x >> 6);
    for (int e = 2 * w + sub; e < num_edges; e += 2 * nWaves) {
        const int h = idx[e], t = idx[num_edges + e];
        const float4* hp = reinterpret_cast<const float4*>(node_emb + (size_t)h * (2 * EMB_D));
        const float4* tp = reinterpret_cast<const float4*>(node_emb + (size_t)t * (2 * EMB_D));
        const float4 hr = hp[j], hi = hp[32 + j], tr = tp[j], ti = tp[32 + j];
        float acc;
        acc  = rr.x * (hr.x * tr.x + hi.x * ti.x) + ri.x * (hr.x * ti.x - hi.x * tr.x);
        acc += rr.y * (hr.y * tr.y + hi.y * ti.y) + ri.y * (hr.y * ti.y - hi.y * tr.y);
        acc += rr.z * (hr.z * tr.z + hi.z * ti.z) + ri.z * (hr.z * ti.z - hi.z * tr.z);
        acc += rr.w * (hr.w * tr.w + hi.w * ti.w) + ri.w * (hr.w * ti.w - hi.w * tr.w);
        #pragma unroll
        for (int off = 1; off <= 16; off <<= 1) acc += __shfl_xor(acc, off, 64);
        if (j == 0) out[e] = acc;
    }
}

extern "C" void kernel_launch(void* const* d_in, const int* in_sizes, int n_in,
                              void* d_out, int out_size, void* d_ws, size_t ws_size,
                              hipStream_t stream) {
    const float* node_emb = (const float*)d_in[0];   // [N, 256] f32
    const float* rel_emb  = (const float*)d_in[1];   // [1, 256] f32
    const int*   idx      = (const int*)d_in[2];     // [2, E] int
    float*       out      = (float*)d_out;           // [E] f32

    const int num_nodes = in_sizes[0] / (2 * EMB_D);
    const int num_edges = in_sizes[2] / 2;

    const size_t tab_bytes = (size_t)num_nodes * 256;
    const size_t need      = tab_bytes + (size_t)num_nodes * sizeof(float);
    const bool idx_ok      = (num_edges % 4) == 0;   // int4 idx loads in the tiled kernel

    if (ws_size >= need && idx_ok) {
        uint2* tab    = (uint2*)d_ws;
        float* scales = (float*)((char*)d_ws + tab_bytes);
        pack_int8_kernel<<<2048, 256, 0, stream>>>(node_emb, tab, scales, num_nodes);
        complex_score_i8_kernel<<<2048, 256, 0, stream>>>(tab, scales, rel_emb, idx, out, num_edges);
    } else {
        complex_score_f32_kernel<<<2048, 256, 0, stream>>>(node_emb, rel_emb, idx, out, num_edges);
    }
}